// Round 1
// baseline (1550.635 us; speedup 1.0000x reference)
//
#include <hip/hip_runtime.h>
#include <hip/hip_bf16.h>

typedef unsigned short u16;
typedef __bf16 bfv8 __attribute__((ext_vector_type(8)));
typedef float  fv4  __attribute__((ext_vector_type(4)));

__device__ __forceinline__ u16 f2bf(float f) {
  union { float f; unsigned u; } c; c.f = f;
  unsigned u = c.u;
  return (u16)((u + 0x7FFFu + ((u >> 16) & 1u)) >> 16);   // RNE
}

// v_cvt_pk_bf16_f32: dst.lo = bf16(lo), dst.hi = bf16(hi)  (RNE, default mode)
__device__ __forceinline__ unsigned cvt2(float lo, float hi) {
  unsigned r;
  asm("v_cvt_pk_bf16_f32 %0, %1, %2" : "=v"(r) : "v"(lo), "v"(hi));
  return r;
}

__device__ __forceinline__ fv4 MFMA(bfv8 a, bfv8 b, fv4 c) {
  return __builtin_amdgcn_mfma_f32_16x16x32_bf16(a, b, c, 0, 0, 0);
}

// ---------------- W transpose + bf16 convert: WT[n][k] = bf16(W[k][n]) ----------------
__global__ __launch_bounds__(256) void transpose_w_bf16(const float* __restrict__ W,
                                                        u16* __restrict__ WT) {
  __shared__ float tile[32][33];
  const int tx = threadIdx.x, ty = threadIdx.y;     // (32,8)
  const int bx = blockIdx.x, by = blockIdx.y;
  #pragma unroll
  for (int i = ty; i < 32; i += 8)
    tile[i][tx] = W[(size_t)(by * 32 + i) * 512 + bx * 32 + tx];
  __syncthreads();
  #pragma unroll
  for (int i = ty; i < 32; i += 8)
    WT[(size_t)(bx * 32 + i) * 512 + by * 32 + tx] = f2bf(tile[tx][i]);
}

// ---------------- C[M,512] = A[M,512] @ W + bias ; WT is [n][k] bf16 ----------------
// 128x128 tile, BK=64, 4 waves in 2x2, each wave a 64x64 sub-tile (4x4 MFMA frags).
// grid = (4, M/128): x = n-tile (fast, A L2 reuse), y = m-tile. block = 256.
template<int A_BF16, int OUT_BF16>
__global__ __launch_bounds__(256) void gemm_bias(const void* __restrict__ Ap,
                                                 const u16* __restrict__ WT,
                                                 const float* __restrict__ bias,
                                                 void* __restrict__ Cp) {
  const int bn = blockIdx.x;
  const int bm = blockIdx.y;
  const int tid = threadIdx.x;
  const int wave = tid >> 6, lane = tid & 63;
  const int q4 = lane >> 4, l16 = lane & 15;
  const int wm = (wave & 1) * 64, wn = (wave >> 1) * 64;

  __shared__ short As[128][72];   // [m][k] bf16, pad 72 (144B rows, 16B aligned)
  __shared__ short Ws[128][72];   // [n][k] bf16

  fv4 acc[4][4] = {};

  const int ar = tid >> 1;              // 128 rows, 2 threads/row
  const int ak = (tid & 1) * 32;        // 32 elems each
  const size_t arow = (size_t)(bm * 128 + ar) * 512;
  const size_t wrow = (size_t)(bn * 128 + ar) * 512;

  for (int k0 = 0; k0 < 512; k0 += 64) {
    __syncthreads();
    if (A_BF16) {
      const u16* A = (const u16*)Ap;
      const u16* s = A + arow + k0 + ak;
      *(bfv8*)&As[ar][ak]      = *(const bfv8*)s;
      *(bfv8*)&As[ar][ak + 8]  = *(const bfv8*)(s + 8);
      *(bfv8*)&As[ar][ak + 16] = *(const bfv8*)(s + 16);
      *(bfv8*)&As[ar][ak + 24] = *(const bfv8*)(s + 24);
    } else {
      const float* A = (const float*)Ap;
      const float* s = A + arow + k0 + ak;
      float4 x0 = *(const float4*)(s);
      float4 x1 = *(const float4*)(s + 4);
      float4 x2 = *(const float4*)(s + 8);
      float4 x3 = *(const float4*)(s + 12);
      float4 x4 = *(const float4*)(s + 16);
      float4 x5 = *(const float4*)(s + 20);
      float4 x6 = *(const float4*)(s + 24);
      float4 x7 = *(const float4*)(s + 28);
      uint4 u0 = { cvt2(x0.x, x0.y), cvt2(x0.z, x0.w), cvt2(x1.x, x1.y), cvt2(x1.z, x1.w) };
      uint4 u1 = { cvt2(x2.x, x2.y), cvt2(x2.z, x2.w), cvt2(x3.x, x3.y), cvt2(x3.z, x3.w) };
      uint4 u2 = { cvt2(x4.x, x4.y), cvt2(x4.z, x4.w), cvt2(x5.x, x5.y), cvt2(x5.z, x5.w) };
      uint4 u3 = { cvt2(x6.x, x6.y), cvt2(x6.z, x6.w), cvt2(x7.x, x7.y), cvt2(x7.z, x7.w) };
      *(uint4*)&As[ar][ak]      = u0;
      *(uint4*)&As[ar][ak + 8]  = u1;
      *(uint4*)&As[ar][ak + 16] = u2;
      *(uint4*)&As[ar][ak + 24] = u3;
    }
    {
      const u16* s = WT + wrow + k0 + ak;
      *(bfv8*)&Ws[ar][ak]      = *(const bfv8*)s;
      *(bfv8*)&Ws[ar][ak + 8]  = *(const bfv8*)(s + 8);
      *(bfv8*)&Ws[ar][ak + 16] = *(const bfv8*)(s + 16);
      *(bfv8*)&Ws[ar][ak + 24] = *(const bfv8*)(s + 24);
    }
    __syncthreads();

    #pragma unroll
    for (int kk = 0; kk < 64; kk += 32) {
      bfv8 a[4], b[4];
      #pragma unroll
      for (int i = 0; i < 4; i++) a[i] = *(const bfv8*)&As[wm + 16 * i + l16][kk + q4 * 8];
      #pragma unroll
      for (int j = 0; j < 4; j++) b[j] = *(const bfv8*)&Ws[wn + 16 * j + l16][kk + q4 * 8];
      #pragma unroll
      for (int i = 0; i < 4; i++)
        #pragma unroll
        for (int j = 0; j < 4; j++)
          acc[i][j] = MFMA(a[i], b[j], acc[i][j]);
    }
  }

  #pragma unroll
  for (int i = 0; i < 4; i++)
    #pragma unroll
    for (int j = 0; j < 4; j++) {
      const int col = bn * 128 + wn + 16 * j + l16;
      const float bb = bias[col];
      #pragma unroll
      for (int r = 0; r < 4; r++) {
        const int row = bm * 128 + wm + 16 * i + q4 * 4 + r;
        const float v = acc[i][j][r] + bb;
        if (OUT_BF16) ((u16*)Cp)[(size_t)row * 512 + col] = f2bf(v);
        else          ((float*)Cp)[(size_t)row * 512 + col] = v;
      }
    }
}

// ---------------- attention core: one block per (b,p) ----------------
__global__ __launch_bounds__(256) void attn_kernel(const u16* __restrict__ Q,
                                                   const u16* __restrict__ K,
                                                   const u16* __restrict__ V,
                                                   const void* __restrict__ maskp,
                                                   u16* __restrict__ O) {
  const int bp = blockIdx.x;          // 0..2047
  const int b = bp >> 9;
  const int tid = threadIdx.x;
  const int wave = tid >> 6, lane = tid & 63;
  const int q4 = lane >> 4, l16 = lane & 15;
  const int wm = (wave & 1) * 32, wn = (wave >> 1) * 32;

  __shared__ __align__(16) char smem[36864];
  short (*Sq)[72]  = (short (*)[72])(smem);            // 9216 B  (phase 1)
  short (*Sk)[72]  = (short (*)[72])(smem + 9216);     // 9216 B  (phase 1)
  float (*Ssc)[65] = (float (*)[65])(smem);            // 16640 B (phase 2-3, overlaps Sq/Sk)
  short (*Sp)[72]  = (short (*)[72])(smem + 18432);    // 9216 B  (phase 3-4)
  short (*Sv)[72]  = (short (*)[72])(smem + 27648);    // 9216 B  (phase 4)
  __shared__ int s_isbool;

  // ---- mask storage detection: int32 layout has bytes[i%4!=0] all zero ----
  if (tid == 0) s_isbool = 0;
  __syncthreads();
  {
    const unsigned char* mb = (const unsigned char*)maskp;
    int loc = 0;
    for (int i = tid; i < 16384; i += 256)
      if ((i & 3) && mb[i]) loc = 1;
    if (loc) atomicOr(&s_isbool, 1);
  }
  __syncthreads();
  const bool isbool = (s_isbool != 0);

  const size_t base = (size_t)bp * 64 * 512;
  const int sr = tid >> 2;              // staging: 64 rows x (4 thr * 16 elem)
  const int sc = (tid & 3) * 16;

  // ---- phase 1: S = Q @ K^T (64x64, K=512) ----
  fv4 acc[2][2] = {};
  for (int d0 = 0; d0 < 512; d0 += 64) {
    __syncthreads();
    const u16* qs = Q + base + (size_t)sr * 512 + d0 + sc;
    *(bfv8*)&Sq[sr][sc]     = *(const bfv8*)qs;
    *(bfv8*)&Sq[sr][sc + 8] = *(const bfv8*)(qs + 8);
    const u16* ks = K + base + (size_t)sr * 512 + d0 + sc;
    *(bfv8*)&Sk[sr][sc]     = *(const bfv8*)ks;
    *(bfv8*)&Sk[sr][sc + 8] = *(const bfv8*)(ks + 8);
    __syncthreads();
    #pragma unroll
    for (int kk = 0; kk < 64; kk += 32) {
      bfv8 a0 = *(const bfv8*)&Sq[wm + l16][kk + q4 * 8];
      bfv8 a1 = *(const bfv8*)&Sq[wm + 16 + l16][kk + q4 * 8];
      bfv8 b0 = *(const bfv8*)&Sk[wn + l16][kk + q4 * 8];
      bfv8 b1 = *(const bfv8*)&Sk[wn + 16 + l16][kk + q4 * 8];
      acc[0][0] = MFMA(a0, b0, acc[0][0]);
      acc[0][1] = MFMA(a0, b1, acc[0][1]);
      acc[1][0] = MFMA(a1, b0, acc[1][0]);
      acc[1][1] = MFMA(a1, b1, acc[1][1]);
    }
  }
  __syncthreads();

  // ---- phase 2: scale + mask -> Ssc (fp32) ----
  const float scale = 0.04419417382415922f;   // 1/sqrt(512)
  {
    const unsigned char* mb = (const unsigned char*)maskp;
    const int* mi = (const int*)maskp;
    const int mbase = b * 4096;
    #pragma unroll
    for (int i = 0; i < 2; i++)
      #pragma unroll
      for (int j = 0; j < 2; j++)
        #pragma unroll
        for (int r = 0; r < 4; r++) {
          const int v = wm + 16 * i + q4 * 4 + r;
          const int c = wn + 16 * j + l16;
          const int mval = isbool ? (int)mb[mbase + v * 64 + c] : mi[mbase + v * 64 + c];
          Ssc[v][c] = mval ? -INFINITY : acc[i][j][r] * scale;
        }
  }
  __syncthreads();

  // ---- phase 3: softmax rows (thread t = row t), write P bf16 ----
  if (tid < 64) {
    float m = -INFINITY;
    for (int i = 0; i < 64; i++) m = fmaxf(m, Ssc[tid][i]);
    float s = 0.f;
    for (int i = 0; i < 64; i++) {
      float e = __expf(Ssc[tid][i] - m);
      Ssc[tid][i] = e;
      s += e;
    }
    const float inv = 1.0f / s;
    for (int i = 0; i < 64; i++)
      Sp[tid][i] = (short)f2bf(Ssc[tid][i] * inv);
  }
  __syncthreads();

  // ---- phase 4: O = P @ V, in 64-wide d chunks ----
  for (int d0 = 0; d0 < 512; d0 += 64) {
    __syncthreads();
    {
      const u16* vs = V + base + (size_t)sr * 512 + d0 + sc;
      u16 tmp[16];
      *(bfv8*)tmp       = *(const bfv8*)vs;
      *(bfv8*)(tmp + 8) = *(const bfv8*)(vs + 8);
      #pragma unroll
      for (int jj = 0; jj < 16; jj++)
        Sv[sc + jj][sr] = (short)tmp[jj];        // Sv[d][r]
    }
    __syncthreads();
    fv4 oac[2][2] = {};
    #pragma unroll
    for (int kk = 0; kk < 64; kk += 32) {
      bfv8 a0 = *(const bfv8*)&Sp[wm + l16][kk + q4 * 8];
      bfv8 a1 = *(const bfv8*)&Sp[wm + 16 + l16][kk + q4 * 8];
      bfv8 b0 = *(const bfv8*)&Sv[wn + l16][kk + q4 * 8];
      bfv8 b1 = *(const bfv8*)&Sv[wn + 16 + l16][kk + q4 * 8];
      oac[0][0] = MFMA(a0, b0, oac[0][0]);
      oac[0][1] = MFMA(a0, b1, oac[0][1]);
      oac[1][0] = MFMA(a1, b0, oac[1][0]);
      oac[1][1] = MFMA(a1, b1, oac[1][1]);
    }
    #pragma unroll
    for (int i = 0; i < 2; i++)
      #pragma unroll
      for (int j = 0; j < 2; j++)
        #pragma unroll
        for (int r = 0; r < 4; r++) {
          const int v = wm + 16 * i + q4 * 4 + r;
          const int c = wn + 16 * j + l16;
          O[base + (size_t)v * 512 + d0 + c] = f2bf(oac[i][j][r]);
        }
  }
}

extern "C" void kernel_launch(void* const* d_in, const int* in_sizes, int n_in,
                              void* d_out, int out_size, void* d_ws, size_t ws_size,
                              hipStream_t stream) {
  (void)in_sizes; (void)n_in; (void)out_size; (void)ws_size;
  const float* queries = (const float*)d_in[0];
  const float* keys    = (const float*)d_in[1];
  const float* values  = (const float*)d_in[2];
  const void*  vmask   = d_in[3];
  const float* Wq  = (const float*)d_in[4];
  const float* bq  = (const float*)d_in[5];
  const float* Wkv = (const float*)d_in[6];
  const float* bkv = (const float*)d_in[7];
  const float* Wo  = (const float*)d_in[8];
  const float* bo  = (const float*)d_in[9];

  // ws layout (256 MiB): [Q bf16: 128MB][O bf16: 128MB]
  //   WqT/WkvT live transiently at O's slot (dead before attn writes O);
  //   WoT lives transiently at Q's slot (written after attn is done with Q).
  // d_out doubles as scratch: [K bf16: 128MB][V bf16: 128MB], clobbered by final GEMM.
  u16* Qb   = (u16*)d_ws;
  u16* Ob   = Qb + 67108864;
  u16* WqT  = Ob;
  u16* WkvT = Ob + 262144;
  u16* WoT  = Qb;
  u16* Kb   = (u16*)d_out;
  u16* Vb   = Kb + 67108864;
  float* out = (float*)d_out;

  dim3 tb(32, 8), tg(16, 16);
  transpose_w_bf16<<<tg, tb, 0, stream>>>(Wq, WqT);
  transpose_w_bf16<<<tg, tb, 0, stream>>>(Wkv, WkvT);

  dim3 gg(4, 1024);   // 128x128 tiles: N/128 = 4, M/128 = 1024
  gemm_bias<0, 1><<<gg, 256, 0, stream>>>((const void*)queries, WqT, bq, (void*)Qb);
  gemm_bias<0, 1><<<gg, 256, 0, stream>>>((const void*)keys,    WkvT, bkv, (void*)Kb);
  gemm_bias<0, 1><<<gg, 256, 0, stream>>>((const void*)values,  WkvT, bkv, (void*)Vb);

  attn_kernel<<<dim3(2048), dim3(256), 0, stream>>>(Qb, Kb, Vb, vmask, Ob);

  transpose_w_bf16<<<tg, tb, 0, stream>>>(Wo, WoT);
  gemm_bias<1, 0><<<gg, 256, 0, stream>>>((const void*)Ob, WoT, bo, (void*)out);
}